// Round 10
// baseline (249.242 us; speedup 1.0000x reference)
//
#include <hip/hip_runtime.h>

#define NLOC  10
#define NGI   13
#define NPAIR 55
#define EPB   64           // elements per chunk
#define TPB   256          // 4 waves; 4 threads per element

// per-buffer floats: nx (EPB*260=16640) + dw (EPB*13=832)
#define BUF_FL   17472
#define W_N      (2 * BUF_FL)       // n table behind the two buffers
#define W_TOT    (W_N + 130)        // 35074 floats = 140296 B (< 160 KiB)

#define NX_GRAN  4160               // 16B granules in nx region
#define TOT_GRAN 4368               // + 208 dw granules (= 17*256 + 16)

typedef float vf2 __attribute__((ext_vector_type(2)));

__device__ __forceinline__ constexpr int pidx(int i, int j) {   // requires i<=j
    return i * NLOC - (i * (i - 1)) / 2 + (j - i);
}

// async global->LDS, 16B/lane; lds base wave-uniform, HW adds lane*16
__device__ __forceinline__ void stage16(const float* gsrc, float* lds) {
    __builtin_amdgcn_global_load_lds(
        (const __attribute__((address_space(1))) void*)gsrc,
        (__attribute__((address_space(3))) void*)lds, 16, 0, 0);
}

__global__ __launch_bounds__(TPB) void fem_kernel(
    const float* __restrict__ r0g,
    const float* __restrict__ cig,
    const float* __restrict__ cng,
    const float* __restrict__ kp,
    const float* __restrict__ dtp,
    const float* __restrict__ nmat,
    const float* __restrict__ nx,
    const float* __restrict__ dwei,
    float* __restrict__ out,
    int nele)
{
    __shared__ float sm[W_TOT];

    const int t       = threadIdx.x;
    const int nchunks = (nele + EPB - 1) / EPB;
    const int gs      = gridDim.x;

    if (t < 130) sm[W_N + t] = nmat[t];   // n table, once per block

    // stage a chunk's nx+dw into buffer b (flat granule copy, coalesced)
    auto stage_chunk = [&](int b, int c) {
        const long ce0   = (long)c * EPB;
        const int  crem  = min(EPB, nele - (int)ce0);
        const int  capnx = crem * 260;
        const int  capdw = crem * 13;
        const float* nxsrc = nx   + (size_t)ce0 * 260;
        const float* dwsrc = dwei + (size_t)ce0 * 13;
        float* ldsb = sm + b * BUF_FL + (t >> 6) * 256;  // wave-uniform base
        #pragma unroll
        for (int k = 0; k < 18; ++k) {
            const int G = k * 256 + t;    // granule; LDS float off = b*BUF_FL + G*4
            if (G < NX_GRAN) {
                if (G * 4 < capnx) stage16(nxsrc + (size_t)G * 4, ldsb + k * 1024);
            } else if (G < TOT_GRAN) {
                const int rel = G - NX_GRAN;
                if (rel * 4 < capdw) stage16(dwsrc + (size_t)rel * 4, ldsb + k * 1024);
            }
        }
    };

    // per-element thread roles (chunk-invariant)
    const int  eloc = t >> 2;
    const int  d    = (t >> 1) & 1;      // spatial dim (stiffness)
    const int  h    = t & 1;             // g-parity (stiffness)
    const int  q    = t & 3;             // g-stride-4 slot (mass, epilogue)
    const float kk  = kp[0];
    const float idt = 1.0f / dtp[0];
    const float* smn = sm + W_N;

    // ---------------- pipelined grid-stride chunk loop -------------------
    int c = blockIdx.x;
    if (c < nchunks) stage_chunk(0, c);
    __syncthreads();                      // drain prologue stage

    int cur = 0;
    for (; c < nchunks; c += gs) {
        const int next = c + gs;
        if (next < nchunks) stage_chunk(cur ^ 1, next);   // issue BEFORE compute;
                                                          // DMA streams under it
        // -------- compute chunk c from buf[cur] --------
        const long e0   = (long)c * EPB;
        const int  rem  = min(EPB, nele - (int)e0);
        const long e    = e0 + eloc;
        const bool live = eloc < rem;
        const long ee   = live ? e : (long)(nele - 1);    // clamp for global reads

        const float* smnx = sm + cur * BUF_FL + eloc * 260 + d * 130;
        const float* smdw = sm + cur * BUF_FL + 16640 + eloc * 13;

        float civ[NLOC], dif[NLOC];
        {
            const vf2* ci2 = reinterpret_cast<const vf2*>(cig + (size_t)ee * 10);
            const vf2* cn2 = reinterpret_cast<const vf2*>(cng + (size_t)ee * 10);
            #pragma unroll
            for (int u2 = 0; u2 < 5; ++u2) {
                vf2 a = ci2[u2], b = cn2[u2];
                civ[2*u2]   = a.x; civ[2*u2+1] = a.y;
                dif[2*u2]   = b.x - a.x; dif[2*u2+1] = b.y - a.y;
            }
        }

        float acc[NPAIR];
        #pragma unroll
        for (int p = 0; p < NPAIR; ++p) acc[p] = 0.0f;
        float r0a[NLOC];
        #pragma unroll
        for (int i = 0; i < NLOC; ++i) r0a[i] = 0.0f;

        // stiffness: dim d, g = 2*it + h (7 iters, last guarded)
        #pragma unroll
        for (int it = 0; it < 7; ++it) {
            const int   graw = 2 * it + h;
            const int   g    = graw < NGI ? graw : NGI - 1;
            const float wv   = graw < NGI ? kk * smdw[g] : 0.0f;
            float col[NLOC];
            #pragma unroll
            for (int l = 0; l < NLOC; ++l) col[l] = smnx[l * 13 + g];
            float u = 0.0f;
            #pragma unroll
            for (int l = 0; l < NLOC; ++l) u = fmaf(col[l], civ[l], u);
            const float uw = u * wv;
            #pragma unroll
            for (int i = 0; i < NLOC; ++i) {
                const float ti = col[i] * wv;
                #pragma unroll
                for (int j = i; j < NLOC; ++j)
                    acc[pidx(i, j)] = fmaf(ti, col[j], acc[pidx(i, j)]);
                r0a[i] = fmaf(-col[i], uw, r0a[i]);
            }
        }

        // mass: g = q + 4*it (4 iters, guarded); r0 += nn/dt*(cn-ci)
        #pragma unroll
        for (int it = 0; it < 4; ++it) {
            const int   graw = q + 4 * it;
            const int   g    = graw < NGI ? graw : NGI - 1;
            const float wv   = graw < NGI ? idt * smdw[g] : 0.0f;
            float ncol[NLOC];
            #pragma unroll
            for (int l = 0; l < NLOC; ++l) ncol[l] = smn[l * 13 + g];
            float wd = 0.0f;
            #pragma unroll
            for (int l = 0; l < NLOC; ++l) wd = fmaf(ncol[l], dif[l], wd);
            #pragma unroll
            for (int i = 0; i < NLOC; ++i) {
                const float ti = ncol[i] * wv;
                #pragma unroll
                for (int j = i; j < NLOC; ++j)
                    acc[pidx(i, j)] = fmaf(ti, ncol[j], acc[pidx(i, j)]);
                r0a[i] = fmaf(ti, wd, r0a[i]);
            }
        }

        // combine the 4 partial sums (quad butterfly — shfl, r9 showed DPP loses)
        #pragma unroll
        for (int p = 0; p < NPAIR; ++p) {
            acc[p] += __shfl_xor(acc[p], 1);
            acc[p] += __shfl_xor(acc[p], 2);
        }
        #pragma unroll
        for (int i = 0; i < NLOC; ++i) {
            r0a[i] += __shfl_xor(r0a[i], 1);
            r0a[i] += __shfl_xor(r0a[i], 2);
        }

        // epilogue: rows split by (i&3)==q, literal indices
        if (live) {
            float* obd = out + (size_t)e * 100;
            float* odg = out + (size_t)nele * 100 + (size_t)e * 10;
            float* oro = out + (size_t)nele * 110 + (size_t)e * 10;
            const float* r0s = r0g + (size_t)e * 10;
            #pragma unroll
            for (int i = 0; i < NLOC; ++i) {
                if ((i & 3) == q) {
                    float row[NLOC];
                    #pragma unroll
                    for (int j = 0; j < NLOC; ++j) {
                        const int lo = i < j ? i : j, hi = i < j ? j : i;
                        row[j] = acc[pidx(lo, hi)];
                    }
                    #pragma unroll
                    for (int u2 = 0; u2 < 5; ++u2) {
                        vf2 v = { row[2*u2], row[2*u2+1] };
                        *reinterpret_cast<vf2*>(obd + i * 10 + 2 * u2) = v;
                    }
                    odg[i] = row[i];
                    oro[i] = r0s[i] + r0a[i];
                }
            }
        }

        __syncthreads();   // drains next-stage DMA (in flight all compute long)
                           // + releases buf[cur] for the following stage
        cur ^= 1;
    }
}

extern "C" void kernel_launch(void* const* d_in, const int* in_sizes, int n_in,
                              void* d_out, int out_size, void* d_ws, size_t ws_size,
                              hipStream_t stream) {
    const float* r0   = (const float*)d_in[0];
    const float* ci   = (const float*)d_in[1];
    const float* cn   = (const float*)d_in[2];
    const float* k    = (const float*)d_in[3];
    const float* dt   = (const float*)d_in[4];
    const float* nmat = (const float*)d_in[5];
    const float* nx   = (const float*)d_in[6];
    const float* dw   = (const float*)d_in[7];
    const int nele = in_sizes[7] / NGI;

    const int nchunks = (nele + EPB - 1) / EPB;
    const int nb = min(256, nchunks);        // 1 block/CU; grid-stride pipeline
    fem_kernel<<<nb, TPB, 0, stream>>>(r0, ci, cn, k, dt, nmat, nx, dw,
                                       (float*)d_out, nele);
}

// Round 12
// 210.676 us; speedup vs baseline: 1.1831x; 1.1831x over previous
//
#include <hip/hip_runtime.h>

#define NLOC  10
#define NGI   13
#define NPAIR 55
#define EPB   32           // elements per chunk
#define TPB   128          // 2 waves; 4 threads per element

// per-buffer float offsets (one chunk's working set, ALL compute inputs)
#define B_NX   0           // EPB*260 = 8320
#define B_DW   8320        // EPB*13  = 416
#define B_R0   8736        // EPB*10  = 320
#define B_CI   9056        // 320
#define B_CN   9376        // 320
#define BUF_FL 9696        // 38784 B per buffer
#define W_N    (2 * BUF_FL)
#define W_TOT  (W_N + 130) // 19522 fl = 78088 B -> 2 blocks/CU

// granule (16B) region END boundaries
#define GE_NX  2080
#define GE_DW  2184
#define GE_R0  2264
#define GE_CI  2344
#define GE_CN  2424        // = 18*128 + 120

typedef float vf2 __attribute__((ext_vector_type(2)));

__device__ __forceinline__ constexpr int pidx(int i, int j) {   // requires i<=j
    return i * NLOC - (i * (i - 1)) / 2 + (j - i);
}

// async global->LDS, 16B/lane; lds base wave-uniform, HW adds lane*16
__device__ __forceinline__ void stage16(const float* gsrc, float* lds) {
    __builtin_amdgcn_global_load_lds(
        (const __attribute__((address_space(1))) void*)gsrc,
        (__attribute__((address_space(3))) void*)lds, 16, 0, 0);
}

__global__ __launch_bounds__(TPB, 1) void fem_kernel(
    const float* __restrict__ r0g,
    const float* __restrict__ cig,
    const float* __restrict__ cng,
    const float* __restrict__ kp,
    const float* __restrict__ dtp,
    const float* __restrict__ nmat,
    const float* __restrict__ nx,
    const float* __restrict__ dwei,
    float* __restrict__ out,
    int nele)
{
    __shared__ float sm[W_TOT];

    const int t       = threadIdx.x;
    const int nchunks = (nele + EPB - 1) / EPB;
    const int gs      = gridDim.x;

    // stage one chunk's FULL working set into buffer b (flat coalesced DMA)
    auto stage_chunk = [&](int b, int c) {
        const long ce0  = (long)c * EPB;
        const int  crem = min(EPB, nele - (int)ce0);
        const float* snx = nx   + (size_t)ce0 * 260;
        const float* sdw = dwei + (size_t)ce0 * 13;
        const float* sr0 = r0g  + (size_t)ce0 * 10;
        const float* sci = cig  + (size_t)ce0 * 10;
        const float* scn = cng  + (size_t)ce0 * 10;
        const int cnx = crem * 260, cdw = crem * 13, c10 = crem * 10;
        float* ldsb = sm + b * BUF_FL + (t >> 6) * 256;  // wave-uniform base
        #pragma unroll
        for (int k = 0; k < 19; ++k) {
            const int G = k * TPB + t;   // granule; LDS float off = b*BUF_FL+G*4
            const float* src; int rel, capf;
            if      (G < GE_NX) { src = snx; rel = G;         capf = cnx; }
            else if (G < GE_DW) { src = sdw; rel = G - GE_NX; capf = cdw; }
            else if (G < GE_R0) { src = sr0; rel = G - GE_DW; capf = c10; }
            else if (G < GE_CI) { src = sci; rel = G - GE_R0; capf = c10; }
            else if (G < GE_CN) { src = scn; rel = G - GE_CI; capf = c10; }
            else continue;
            if (rel * 4 < capf) stage16(src + (size_t)rel * 4, ldsb + k * TPB * 4);
        }
    };

    // per-element thread roles (chunk-invariant)
    const int  eloc = t >> 2;
    const int  d    = (t >> 1) & 1;      // spatial dim (stiffness)
    const int  h    = t & 1;             // g-parity (stiffness)
    const int  q    = t & 3;             // g-stride-4 slot (mass, epilogue)
    const float kk  = kp[0];
    const float idt = 1.0f / dtp[0];
    const float* smn = sm + W_N;

    // ---------------- pipelined grid-stride chunk loop -------------------
    int c = blockIdx.x;
    if (c < nchunks) stage_chunk(0, c);
    for (int w = t; w < 130; w += TPB) sm[W_N + w] = nmat[w];   // FULL table (r11 bug: t<130 missed 128,129 at TPB=128)
    __syncthreads();                      // drain prologue stage

    int cur = 0;
    for (; c < nchunks; c += gs) {
        const int next = c + gs;
        if (next < nchunks) stage_chunk(cur ^ 1, next);  // DMA streams under compute

        // -------- compute chunk c from buf[cur]: ZERO global loads --------
        const long e0   = (long)c * EPB;
        const int  rem  = min(EPB, nele - (int)e0);
        const long e    = e0 + eloc;
        const bool live = eloc < rem;

        const float* bb   = sm + cur * BUF_FL;
        const float* smnx = bb + B_NX + eloc * 260 + d * 130;
        const float* smdw = bb + B_DW + eloc * 13;
        const float* smr0 = bb + B_R0 + eloc * 10;
        const float* smci = bb + B_CI + eloc * 10;
        const float* smcn = bb + B_CN + eloc * 10;

        float civ[NLOC], dif[NLOC];
        #pragma unroll
        for (int l = 0; l < NLOC; ++l) civ[l] = smci[l];
        #pragma unroll
        for (int l = 0; l < NLOC; ++l) dif[l] = smcn[l] - civ[l];

        float acc[NPAIR];
        #pragma unroll
        for (int p = 0; p < NPAIR; ++p) acc[p] = 0.0f;
        float r0a[NLOC];
        #pragma unroll
        for (int i = 0; i < NLOC; ++i) r0a[i] = 0.0f;

        // stiffness: dim d, g = 2*it + h (7 iters, last guarded)
        #pragma unroll
        for (int it = 0; it < 7; ++it) {
            const int   graw = 2 * it + h;
            const int   g    = graw < NGI ? graw : NGI - 1;
            const float wv   = graw < NGI ? kk * smdw[g] : 0.0f;
            float col[NLOC];
            #pragma unroll
            for (int l = 0; l < NLOC; ++l) col[l] = smnx[l * 13 + g];
            float u = 0.0f;
            #pragma unroll
            for (int l = 0; l < NLOC; ++l) u = fmaf(col[l], civ[l], u);
            const float uw = u * wv;
            #pragma unroll
            for (int i = 0; i < NLOC; ++i) {
                const float ti = col[i] * wv;
                #pragma unroll
                for (int j = i; j < NLOC; ++j)
                    acc[pidx(i, j)] = fmaf(ti, col[j], acc[pidx(i, j)]);
                r0a[i] = fmaf(-col[i], uw, r0a[i]);
            }
        }

        // mass: g = q + 4*it (4 iters, guarded); r0 += nn/dt*(cn-ci)
        #pragma unroll
        for (int it = 0; it < 4; ++it) {
            const int   graw = q + 4 * it;
            const int   g    = graw < NGI ? graw : NGI - 1;
            const float wv   = graw < NGI ? idt * smdw[g] : 0.0f;
            float ncol[NLOC];
            #pragma unroll
            for (int l = 0; l < NLOC; ++l) ncol[l] = smn[l * 13 + g];
            float wd = 0.0f;
            #pragma unroll
            for (int l = 0; l < NLOC; ++l) wd = fmaf(ncol[l], dif[l], wd);
            #pragma unroll
            for (int i = 0; i < NLOC; ++i) {
                const float ti = ncol[i] * wv;
                #pragma unroll
                for (int j = i; j < NLOC; ++j)
                    acc[pidx(i, j)] = fmaf(ti, ncol[j], acc[pidx(i, j)]);
                r0a[i] = fmaf(ti, wd, r0a[i]);
            }
        }

        // combine the 4 partial sums (quad butterfly; shfl — r9 showed DPP loses)
        #pragma unroll
        for (int p = 0; p < NPAIR; ++p) {
            acc[p] += __shfl_xor(acc[p], 1);
            acc[p] += __shfl_xor(acc[p], 2);
        }
        #pragma unroll
        for (int i = 0; i < NLOC; ++i) {
            r0a[i] += __shfl_xor(r0a[i], 1);
            r0a[i] += __shfl_xor(r0a[i], 2);
        }

        // epilogue: rows split by (i&3)==q, literal indices
        if (live) {
            float* obd = out + (size_t)e * 100;
            float* odg = out + (size_t)nele * 100 + (size_t)e * 10;
            float* oro = out + (size_t)nele * 110 + (size_t)e * 10;
            #pragma unroll
            for (int i = 0; i < NLOC; ++i) {
                if ((i & 3) == q) {
                    float row[NLOC];
                    #pragma unroll
                    for (int j = 0; j < NLOC; ++j) {
                        const int lo = i < j ? i : j, hi = i < j ? j : i;
                        row[j] = acc[pidx(lo, hi)];
                    }
                    #pragma unroll
                    for (int u2 = 0; u2 < 5; ++u2) {
                        vf2 v = { row[2*u2], row[2*u2+1] };
                        *reinterpret_cast<vf2*>(obd + i * 10 + 2 * u2) = v;
                    }
                    odg[i] = row[i];
                    oro[i] = smr0[i] + r0a[i];
                }
            }
        }

        __syncthreads();   // drains next-stage DMA + stores (both had the whole
                           // compute phase to land) and releases buf[cur]
        cur ^= 1;
    }
}

extern "C" void kernel_launch(void* const* d_in, const int* in_sizes, int n_in,
                              void* d_out, int out_size, void* d_ws, size_t ws_size,
                              hipStream_t stream) {
    const float* r0   = (const float*)d_in[0];
    const float* ci   = (const float*)d_in[1];
    const float* cn   = (const float*)d_in[2];
    const float* k    = (const float*)d_in[3];
    const float* dt   = (const float*)d_in[4];
    const float* nmat = (const float*)d_in[5];
    const float* nx   = (const float*)d_in[6];
    const float* dw   = (const float*)d_in[7];
    const int nele = in_sizes[7] / NGI;

    const int nchunks = (nele + EPB - 1) / EPB;
    const int nb = min(512, nchunks);        // 2 pipelines/CU, grid-stride
    fem_kernel<<<nb, TPB, 0, stream>>>(r0, ci, cn, k, dt, nmat, nx, dw,
                                       (float*)d_out, nele);
}